// Round 3
// baseline (602.140 us; speedup 1.0000x reference)
//
#include <hip/hip_runtime.h>
#include <hip/hip_bf16.h>

// f32 in/out. Internal: bf16 MFMA. q/kv projections 1-term bf16 (W hi only);
// o-proj exact 2-term via K=512 packed [Wo_hi | Wo_lo]. Weights pre-packed in
// k_prep into the exact LDS tile image consumed by global_load_lds(16B).
// r6: k_qkv occupancy 3->5 blocks/CU (LDS 32KB x5 = 160KB exact; VGPR 72).
// k_oproj ported to the r4 structure: A (bf16 ao) direct global->reg with
// ping-pong prefetch, B double-buffered via gll16 (1 barrier/iter), packO
// XOR-swizzled like packQ (read at swzlq) -> conflict-free ds_read_b128.
// Accumulation order unchanged -> bit-identical outputs (absmax 0.0078).
typedef __bf16 bf16;
typedef __bf16 bf16x8 __attribute__((ext_vector_type(8)));
typedef float  f32x4  __attribute__((ext_vector_type(4)));

#define DEVINL __device__ __forceinline__

DEVINL void gll16(const void* g, void* l) {
  __builtin_amdgcn_global_load_lds(
      (const __attribute__((address_space(1))) unsigned int*)g,
      (__attribute__((address_space(3))) unsigned int*)l, 16, 0, 0);
}

// ---------------------------------------------------------------------------
// Weight pack. Tile image (per n-tile of 128, per k-iter of 64):
//   1024 slots of 16B; slot s: h=s>>9 (k-half of 32), row=(s&511)>>2, kg=s&3
//   holds W[k0 + h*32 + kg*8 + e][n0+row] for e=0..7  (transposed+bf16).
// Both packQ and packO swizzle the kg slot: kgs = kg ^ ((row>>1)&3) so the
// consumer's ds_read_b128 at (row, lq^((lm>>1)&3)) is bank-conflict-free.
// packQ: 6 n-tiles (q:0-1, k:2-3, v:4-5) x 4 k-iters (hi only).
// packO: 2 n-tiles x 8 k-iters (iters 0-3 = Wo_hi, 4-7 = Wo_lo).
// ---------------------------------------------------------------------------
__global__ void k_prep(const float* __restrict__ Wq, const float* __restrict__ Wk,
                       const float* __restrict__ Wv, const float* __restrict__ Wo,
                       bf16* __restrict__ packQ, bf16* __restrict__ packO) {
  const int n = threadIdx.x;   // dest column 0..255
  const int k = blockIdx.x;    // source k 0..255
  const int m = blockIdx.y;    // 0:Wq 1:Wk 2:Wv 3:Wo-hi 4:Wo-lo
  const int kk = k & 63, iter4 = k >> 6;
  const int h = kk >> 5, kg = (kk >> 3) & 3, e = k & 7;
  if (m < 3) {
    const float* W = (m == 0) ? Wq : (m == 1) ? Wk : Wv;
    const bf16 v = (bf16)W[k * 256 + n];
    const int nglob = m * 256 + n;
    const int tile = nglob >> 7, row = nglob & 127;
    const int kgs = kg ^ ((row >> 1) & 3);   // bank-swizzle (matched in k_qkv)
    packQ[(size_t)((tile * 4 + iter4) * 1024 + h * 512 + row * 4 + kgs) * 8 + e] = v;
  } else {
    const float w = Wo[k * 256 + n];
    const bf16 hi = (bf16)w;
    const bf16 v = (m == 3) ? hi : (bf16)(w - (float)hi);
    const int iter = (m - 3) * 4 + iter4;
    const int tile = n >> 7, row = n & 127;
    const int kgs = kg ^ ((row >> 1) & 3);   // bank-swizzle (matched in k_oproj)
    packO[(size_t)((tile * 8 + iter) * 1024 + h * 512 + row * 4 + kgs) * 8 + e] = v;
  }
}

// ---------------------------------------------------------------------------
// Fused q/kv projection. 128x128 tile, BK=64 (4 iters). 4 waves = 4 disjoint
// 32-row m-strips x full 128 cols. A (f32) loaded global->reg per wave
// (lane-private fragments), cvt->bf16 in-register. B double-buffered in LDS
// via gll16 from swizzled packQ; prefetch(i+1) issued before compute(i); one
// __syncthreads per iter. 5 blocks/CU (32KB LDS x5 = 160KB) for latency
// hiding — the r4 measurement showed BW 1.7 TB/s at ~2.4 resident blocks.
// XCD swizzle: 6 n-siblings of one m-tile adjacent on one XCD (A L2 reuse).
// ---------------------------------------------------------------------------
__global__ __launch_bounds__(256, 5) void k_qkv(
    const float* __restrict__ q, const float* __restrict__ kv,
    const bf16* __restrict__ packQ,
    const float* __restrict__ bq, const float* __restrict__ bk,
    const float* __restrict__ bvv,
    bf16* __restrict__ qp, bf16* __restrict__ kp, bf16* __restrict__ vp) {
  __shared__ __align__(16) bf16 Bs[2][2][128 * 32];   // [buf][k-half][row*32+kg*8+e]

  const int g = blockIdx.x, xcd = g & 7, s = g >> 3;
  const int nb = s % 6, mh = s / 6;
  const int m0 = (mh * 8 + xcd) * 128;
  const float* A = (nb < 2) ? q : kv;

  const int tid = threadIdx.x, lane = tid & 63, wave = tid >> 6;
  const int lm = lane & 15, lq = lane >> 4;
  const int swzlq = lq ^ ((lm >> 1) & 3);
  const int mw = wave * 32;

  f32x4 acc[2][8];
#pragma unroll
  for (int t = 0; t < 2; ++t)
#pragma unroll
    for (int nf = 0; nf < 8; ++nf) acc[t][nf] = (f32x4)0.0f;

  const bf16* pbase = packQ + (size_t)nb * 4 * 8192;
  // A fragment row base: lane lm owns row (mw + t*16 + lm), k-cols lq*8..+7
  const float* arow0 = A + (size_t)(m0 + mw + lm) * 256 + lq * 8;
  const float* arow1 = arow0 + (size_t)16 * 256;

  float4 ar[2][2][2];   // [t][ks][pair] — prefetched A f32, static-indexed only

  auto stageB = [&](int it, int buf) {
    const bf16* pit = pbase + it * 8192;
#pragma unroll
    for (int u = 0; u < 4; ++u) {
      const int c = u * 256 + tid;
      bf16* dst = (u < 2) ? &Bs[buf][0][c * 8] : &Bs[buf][1][(c - 512) * 8];
      gll16(pit + c * 8, dst);
    }
  };
  auto loadA = [&](int it) {
#pragma unroll
    for (int t = 0; t < 2; ++t)
#pragma unroll
      for (int ks = 0; ks < 2; ++ks) {
        const float* p = (t == 0 ? arow0 : arow1) + it * 64 + ks * 32;
        ar[t][ks][0] = *(const float4*)(p);
        ar[t][ks][1] = *(const float4*)(p + 4);
      }
  };

  // prologue: stage iter 0 (B->LDS buf0, A->regs), drain, barrier
  stageB(0, 0);
  loadA(0);
  __syncthreads();

#pragma unroll
  for (int i = 0; i < 4; ++i) {
    const int cur = i & 1;
    // prefetch next tile FIRST (loads stay in flight across compute)
    if (i < 3) stageB(i + 1, cur ^ 1);

    // cvt current A (regs already drained by previous __syncthreads)
    bf16x8 av[2][2];
#pragma unroll
    for (int t = 0; t < 2; ++t)
#pragma unroll
      for (int ks = 0; ks < 2; ++ks) {
        const float4 f0 = ar[t][ks][0], f1 = ar[t][ks][1];
        bf16x8 v;
        v[0] = (bf16)f0.x; v[1] = (bf16)f0.y; v[2] = (bf16)f0.z; v[3] = (bf16)f0.w;
        v[4] = (bf16)f1.x; v[5] = (bf16)f1.y; v[6] = (bf16)f1.z; v[7] = (bf16)f1.w;
        av[t][ks] = v;
      }
    if (i < 3) loadA(i + 1);   // WAR on ar after cvt consumed it

    // compute on current buffer
#pragma unroll
    for (int ks = 0; ks < 2; ++ks) {
      bf16x8 bvf[8];
#pragma unroll
      for (int nf = 0; nf < 8; ++nf)
        bvf[nf] = *(const bf16x8*)&Bs[cur][ks][(nf * 16 + lm) * 32 + swzlq * 8];
#pragma unroll
      for (int t = 0; t < 2; ++t)
#pragma unroll
        for (int nf = 0; nf < 8; ++nf)
          acc[t][nf] = __builtin_amdgcn_mfma_f32_16x16x32_bf16(av[t][ks], bvf[nf], acc[t][nf], 0, 0, 0);
    }
    // single barrier per iter: vmcnt(0) drain of prefetch lands post-MFMA
    if (i < 3) __syncthreads();
  }

  // Epilogue. C layout: col = lane&15, row = (lane>>4)*4 + reg.
  const int ncbase = (nb * 128) & 255;
  bf16* op = (nb < 2) ? qp : (nb < 4) ? kp : vp;
  const float* bp = (nb < 2) ? bq : (nb < 4) ? bk : bvv;
#pragma unroll
  for (int t = 0; t < 2; ++t)
#pragma unroll
    for (int nf = 0; nf < 8; ++nf) {
      const int nc = ncbase + nf * 16 + lm;
      const float bval = bp[nc];
#pragma unroll
      for (int r = 0; r < 4; ++r) {
        const int mg = m0 + mw + t * 16 + lq * 4 + r;
        op[(size_t)mg * 256 + nc] = (bf16)(acc[t][nf][r] + bval);
      }
    }
}

// ---------------------------------------------------------------------------
// Output projection: exact 2-term as K=512 GEMM (iters 0-3 hi, 4-7 lo; A
// re-read — XCD-local L2 holds the 4MB slice so the 2nd pass is an L2 hit).
// r6 structure = k_qkv's: 4 waves = 32-row strips, A (bf16) global->reg with
// ping-pong prefetch (arA/arB, static-indexed), B double-buffered via gll16
// from swizzled packO, 1 barrier/iter. Accumulation order over k identical to
// the old 64x64-wave version -> bit-identical out.
// ---------------------------------------------------------------------------
__global__ __launch_bounds__(256, 4) void k_oproj(
    const bf16* __restrict__ ao, const bf16* __restrict__ packO,
    const float* __restrict__ bo, float* __restrict__ out) {
  __shared__ __align__(16) bf16 Bs[2][2][128 * 32];   // [buf][k-half][...]

  const int g = blockIdx.x, xcd = g & 7, s = g >> 3;
  const int nb = s & 1, mh = s >> 1;
  const int m0 = (mh * 8 + xcd) * 128;

  const int tid = threadIdx.x, lane = tid & 63, wave = tid >> 6;
  const int lm = lane & 15, lq = lane >> 4;
  const int swzlq = lq ^ ((lm >> 1) & 3);
  const int mw = wave * 32;

  f32x4 acc[2][8];
#pragma unroll
  for (int t = 0; t < 2; ++t)
#pragma unroll
    for (int nf = 0; nf < 8; ++nf) acc[t][nf] = (f32x4)0.0f;

  const bf16* pbase = packO + (size_t)nb * 8 * 8192;
  const bf16* arow0 = ao + (size_t)(m0 + mw + lm) * 256 + lq * 8;
  const bf16* arow1 = arow0 + (size_t)16 * 256;

  auto stageB = [&](int it, int buf) {
    const bf16* pit = pbase + (size_t)it * 8192;
#pragma unroll
    for (int u = 0; u < 4; ++u) {
      const int c = u * 256 + tid;
      bf16* dst = (u < 2) ? &Bs[buf][0][c * 8] : &Bs[buf][1][(c - 512) * 8];
      gll16(pit + c * 8, dst);
    }
  };

  bf16x8 arA[2][2], arB[2][2];   // ping-pong A fragments (static-indexed)
  auto loadA = [&](int it, bf16x8 (&dst)[2][2]) {
    const int kA = (it & 3) * 64;   // iters 4-7 re-read same A (hi/lo terms)
#pragma unroll
    for (int t = 0; t < 2; ++t)
#pragma unroll
      for (int ks = 0; ks < 2; ++ks)
        dst[t][ks] = *(const bf16x8*)((t == 0 ? arow0 : arow1) + kA + ks * 32);
  };
  auto computeIter = [&](const bf16x8 (&av)[2][2], int cur) {
#pragma unroll
    for (int ks = 0; ks < 2; ++ks) {
      bf16x8 bvf[8];
#pragma unroll
      for (int nf = 0; nf < 8; ++nf)
        bvf[nf] = *(const bf16x8*)&Bs[cur][ks][(nf * 16 + lm) * 32 + swzlq * 8];
#pragma unroll
      for (int t = 0; t < 2; ++t)
#pragma unroll
        for (int nf = 0; nf < 8; ++nf)
          acc[t][nf] = __builtin_amdgcn_mfma_f32_16x16x32_bf16(av[t][ks], bvf[nf], acc[t][nf], 0, 0, 0);
    }
  };

  stageB(0, 0);
  loadA(0, arA);
  __syncthreads();

#pragma unroll
  for (int i = 0; i < 8; ++i) {
    const int cur = i & 1;
    if (i < 7) {
      stageB(i + 1, cur ^ 1);
      if (cur == 0) loadA(i + 1, arB);
      else          loadA(i + 1, arA);
    }
    if (cur == 0) computeIter(arA, cur);
    else          computeIter(arB, cur);
    if (i < 7) __syncthreads();
  }

  // Epilogue. C layout: col = lane&15, row = (lane>>4)*4 + reg. f32 out.
#pragma unroll
  for (int t = 0; t < 2; ++t)
#pragma unroll
    for (int nf = 0; nf < 8; ++nf) {
      const int nglob = nb * 128 + nf * 16 + lm;
      const float bval = bo[nglob];
#pragma unroll
      for (int r = 0; r < 4; ++r) {
        const int mg = m0 + mw + t * 16 + lq * 4 + r;
        out[(size_t)mg * 256 + nglob] = acc[t][nf][r] + bval;
      }
    }
}

// ---------------------------------------------------------------------------
// Windowed attention (unchanged).
// ---------------------------------------------------------------------------
__global__ __launch_bounds__(256) void k_attn(
    const bf16* __restrict__ qp, const bf16* __restrict__ kp,
    const bf16* __restrict__ vp, bf16* __restrict__ ao) {
  __shared__ __align__(16) bf16 smem[3 * 64 * 136];
  bf16* Qs = smem;
  bf16* Ks = smem + 64 * 136;
  bf16* Vs = smem + 2 * 64 * 136;
  bf16* Ps = smem;
  bf16* Os = Vs;

  const int tid = threadIdx.x;
  const int lane = tid & 63;
  const int hl = tid >> 6;
  const int bw = blockIdx.x;
  const int b = bw >> 8;
  const int w = bw & 255;
  const int wy = w >> 4, wx = w & 15;
  const int ch0 = blockIdx.y * 128;

#pragma unroll
  for (int i = 0; i < 4; ++i) {
    const int c = i * 256 + tid;
    const int t = c >> 4;
    const int off = (c & 15) * 8;
    const int ty = t >> 3, tx = t & 7;
    const size_t gr = ((size_t)(b * 128 + wy * 8 + ty)) * 128 + wx * 8 + tx;
    const size_t gi = gr * 256 + ch0 + off;
    const int li = t * 136 + off;
    *(uint4*)&Qs[li] = *(const uint4*)&qp[gi];
    *(uint4*)&Ks[li] = *(const uint4*)&kp[gi];
    *(uint4*)&Vs[li] = *(const uint4*)&vp[gi];
  }
  __syncthreads();

  const int chh = hl * 32;
  const int lm = lane & 15;
  const int lq = lane >> 4;

  bf16x8 qa[4], kb[4];
#pragma unroll
  for (int t = 0; t < 4; ++t)
    qa[t] = *(const bf16x8*)&Qs[(t * 16 + lm) * 136 + chh + lq * 8];
#pragma unroll
  for (int t = 0; t < 4; ++t)
    kb[t] = *(const bf16x8*)&Ks[(t * 16 + lm) * 136 + chh + lq * 8];

  f32x4 s[4][4];
#pragma unroll
  for (int i = 0; i < 4; ++i)
#pragma unroll
    for (int j = 0; j < 4; ++j) s[i][j] = (f32x4)0.0f;
#pragma unroll
  for (int i = 0; i < 4; ++i)
#pragma unroll
    for (int j = 0; j < 4; ++j)
      s[i][j] = __builtin_amdgcn_mfma_f32_16x16x32_bf16(qa[i], kb[j], s[i][j], 0, 0, 0);

  const float scale = 0.17677669529663687f;
  float rl[4][4];
#pragma unroll
  for (int mt = 0; mt < 4; ++mt) {
#pragma unroll
    for (int r = 0; r < 4; ++r) {
      float mx = fmaxf(fmaxf(s[mt][0][r], s[mt][1][r]), fmaxf(s[mt][2][r], s[mt][3][r]));
      mx = fmaxf(mx, __shfl_xor(mx, 1));
      mx = fmaxf(mx, __shfl_xor(mx, 2));
      mx = fmaxf(mx, __shfl_xor(mx, 4));
      mx = fmaxf(mx, __shfl_xor(mx, 8));
      float sum = 0.f;
#pragma unroll
      for (int nt = 0; nt < 4; ++nt) {
        const float p = __expf((s[mt][nt][r] - mx) * scale);
        s[mt][nt][r] = p;
        sum += p;
      }
      sum += __shfl_xor(sum, 1);
      sum += __shfl_xor(sum, 2);
      sum += __shfl_xor(sum, 4);
      sum += __shfl_xor(sum, 8);
      rl[mt][r] = 1.0f / sum;
    }
  }

  __syncthreads();

  bf16* Ph = Ps + hl * 4096;
#pragma unroll
  for (int mt = 0; mt < 4; ++mt)
#pragma unroll
    for (int nt = 0; nt < 4; ++nt)
#pragma unroll
      for (int r = 0; r < 4; ++r) {
        const int qrow = mt * 16 + lq * 4 + r;
        const int kcol = nt * 16 + lm;
        Ph[qrow * 64 + (((kcol >> 3) ^ (qrow & 7)) << 3) + (kcol & 7)] = (bf16)s[mt][nt][r];
      }

  f32x4 o[4][2];
#pragma unroll
  for (int i = 0; i < 4; ++i) { o[i][0] = (f32x4)0.0f; o[i][1] = (f32x4)0.0f; }
#pragma unroll
  for (int ks = 0; ks < 2; ++ks) {
    bf16x8 pa[4];
#pragma unroll
    for (int mt = 0; mt < 4; ++mt) {
      const int qrow = mt * 16 + lm;
      const int gsel = ks * 4 + lq;
      pa[mt] = *(const bf16x8*)&Ph[qrow * 64 + ((gsel ^ (qrow & 7)) << 3)];
    }
    bf16x8 vbf[2];
#pragma unroll
    for (int ntd = 0; ntd < 2; ++ntd) {
      const int d = ntd * 16 + lm;
      bf16x8 tv;
#pragma unroll
      for (int j = 0; j < 8; ++j)
        tv[j] = Vs[(ks * 32 + lq * 8 + j) * 136 + chh + d];
      vbf[ntd] = tv;
    }
#pragma unroll
    for (int mt = 0; mt < 4; ++mt)
#pragma unroll
      for (int ntd = 0; ntd < 2; ++ntd)
        o[mt][ntd] = __builtin_amdgcn_mfma_f32_16x16x32_bf16(pa[mt], vbf[ntd], o[mt][ntd], 0, 0, 0);
  }

  __syncthreads();

#pragma unroll
  for (int mt = 0; mt < 4; ++mt)
#pragma unroll
    for (int ntd = 0; ntd < 2; ++ntd)
#pragma unroll
      for (int r = 0; r < 4; ++r) {
        const int qrow = mt * 16 + lq * 4 + r;
        const int d = ntd * 16 + lm;
        Os[qrow * 136 + chh + d] = (bf16)(o[mt][ntd][r] * rl[mt][r]);
      }
  __syncthreads();

#pragma unroll
  for (int i = 0; i < 4; ++i) {
    const int c = i * 256 + tid;
    const int t = c >> 4;
    const int off = (c & 15) * 8;
    const int ty = t >> 3, tx = t & 7;
    const size_t gr = ((size_t)(b * 128 + wy * 8 + ty)) * 128 + wx * 8 + tx;
    *(uint4*)&ao[gr * 256 + ch0 + off] = *(const uint4*)&Os[t * 136 + off];
  }
}

// ---------------------------------------------------------------------------
extern "C" void kernel_launch(void* const* d_in, const int* in_sizes, int n_in,
                              void* d_out, int out_size, void* d_ws, size_t ws_size,
                              hipStream_t stream) {
  const float* q  = (const float*)d_in[0];
  const float* kv = (const float*)d_in[1];
  const float* Wq = (const float*)d_in[2];
  const float* bq = (const float*)d_in[3];
  const float* Wk = (const float*)d_in[4];
  const float* bk = (const float*)d_in[5];
  const float* Wv = (const float*)d_in[6];
  const float* bv = (const float*)d_in[7];
  const float* Wo = (const float*)d_in[8];
  const float* bo = (const float*)d_in[9];
  float* out = (float*)d_out;

  char* ws = (char*)d_ws;
  bf16* packQ = (bf16*)(ws + 0);        // 393216 B
  bf16* packO = (bf16*)(ws + 393216);   // 262144 B
  const size_t PLANE = (size_t)65536 * 256 * 2;
  bf16* qp = (bf16*)(ws + 1048576);
  bf16* kp = (bf16*)(ws + 1048576 + PLANE);
  bf16* vp = (bf16*)(ws + 1048576 + 2 * PLANE);
  bf16* ao = (bf16*)(ws + 1048576 + 3 * PLANE);
  if (ws_size < 1048576 + 4 * PLANE) return;

  k_prep<<<dim3(256, 5), 256, 0, stream>>>(Wq, Wk, Wv, Wo, packQ, packO);
  k_qkv<<<3072, 256, 0, stream>>>(q, kv, packQ, bq, bk, bv, qp, kp, vp);
  k_attn<<<dim3(1024, 2), 256, 0, stream>>>(qp, kp, vp, ao);
  k_oproj<<<1024, 256, 0, stream>>>(ao, packO, bo, out);
}

// Round 4
// 288.032 us; speedup vs baseline: 2.0905x; 2.0905x over previous
//
#include <hip/hip_runtime.h>
#include <hip/hip_bf16.h>

// f32 in/out. Internal: bf16 MFMA. q/kv projections 1-term bf16 (W hi only);
// o-proj exact 2-term via K=512 packed [Wo_hi | Wo_lo]. Weights pre-packed in
// k_prep into the exact LDS tile image consumed by global_load_lds(16B).
// r7: segment-rate fix. r6's launch_bounds(256,5) spilled (VGPR 48, 1.3GB
// scratch) — reverted to (256,3). A-staging rebuilt for coalescing: linear
// global loads (each instr = 4 rows x 256B = 8x128B segments, vs 16x16B
// scattered in r4), cvt in reg, ds_write into granule-XOR-swizzled A-image
// (g ^= row&7), fragments via ds_read_b128 (write+read conflict-free).
// B path unchanged (gll16 from kg-swizzled pack). 2 cheap barriers/iter.
// Same values + MFMA order -> bit-identical (absmax 0.0078).
typedef __bf16 bf16;
typedef __bf16 bf16x8 __attribute__((ext_vector_type(8)));
typedef __bf16 bf16x4 __attribute__((ext_vector_type(4)));
typedef float  f32x4  __attribute__((ext_vector_type(4)));

#define DEVINL __device__ __forceinline__

DEVINL void gll16(const void* g, void* l) {
  __builtin_amdgcn_global_load_lds(
      (const __attribute__((address_space(1))) unsigned int*)g,
      (__attribute__((address_space(3))) unsigned int*)l, 16, 0, 0);
}

// ---------------------------------------------------------------------------
// Weight pack. Tile image (per n-tile of 128, per k-iter of 64):
//   1024 slots of 16B; slot s: h=s>>9 (k-half of 32), row=(s&511)>>2, kg=s&3
//   holds W[k0 + h*32 + kg*8 + e][n0+row] for e=0..7  (transposed+bf16).
// Both packQ and packO swizzle the kg slot: kgs = kg ^ ((row>>1)&3) so the
// consumer's ds_read_b128 at (row, lq^((lm>>1)&3)) is bank-conflict-free.
// packQ: 6 n-tiles (q:0-1, k:2-3, v:4-5) x 4 k-iters (hi only).
// packO: 2 n-tiles x 8 k-iters (iters 0-3 = Wo_hi, 4-7 = Wo_lo).
// ---------------------------------------------------------------------------
__global__ void k_prep(const float* __restrict__ Wq, const float* __restrict__ Wk,
                       const float* __restrict__ Wv, const float* __restrict__ Wo,
                       bf16* __restrict__ packQ, bf16* __restrict__ packO) {
  const int n = threadIdx.x;   // dest column 0..255
  const int k = blockIdx.x;    // source k 0..255
  const int m = blockIdx.y;    // 0:Wq 1:Wk 2:Wv 3:Wo-hi 4:Wo-lo
  const int kk = k & 63, iter4 = k >> 6;
  const int h = kk >> 5, kg = (kk >> 3) & 3, e = k & 7;
  if (m < 3) {
    const float* W = (m == 0) ? Wq : (m == 1) ? Wk : Wv;
    const bf16 v = (bf16)W[k * 256 + n];
    const int nglob = m * 256 + n;
    const int tile = nglob >> 7, row = nglob & 127;
    const int kgs = kg ^ ((row >> 1) & 3);   // bank-swizzle (matched in k_qkv)
    packQ[(size_t)((tile * 4 + iter4) * 1024 + h * 512 + row * 4 + kgs) * 8 + e] = v;
  } else {
    const float w = Wo[k * 256 + n];
    const bf16 hi = (bf16)w;
    const bf16 v = (m == 3) ? hi : (bf16)(w - (float)hi);
    const int iter = (m - 3) * 4 + iter4;
    const int tile = n >> 7, row = n & 127;
    const int kgs = kg ^ ((row >> 1) & 3);   // bank-swizzle (matched in k_oproj)
    packO[(size_t)((tile * 8 + iter) * 1024 + h * 512 + row * 4 + kgs) * 8 + e] = v;
  }
}

// ---------------------------------------------------------------------------
// Fused q/kv projection. 128x128 tile, BK=64 (4 iters). 4 waves = 4 disjoint
// 32-row m-strips x full 128 cols. A (f32) loaded LINEARLY (per instr: 4 rows
// x 256B contiguous = 8x128B segments), cvt->bf16, ds_write_b64 into A-image
// with granule swizzle g^=(row&7); fragments ds_read_b128 conflict-free.
// B double-buffered via gll16 from swizzled packQ. Per iter: issue next B+A,
// compute, barrier (drain overlapped by compute), write A-image, barrier.
// XCD swizzle: 6 n-siblings of one m-tile adjacent on one XCD (A L2 reuse).
// ---------------------------------------------------------------------------
__global__ __launch_bounds__(256, 3) void k_qkv(
    const float* __restrict__ q, const float* __restrict__ kv,
    const bf16* __restrict__ packQ,
    const float* __restrict__ bq, const float* __restrict__ bk,
    const float* __restrict__ bvv,
    bf16* __restrict__ qp, bf16* __restrict__ kp, bf16* __restrict__ vp) {
  __shared__ __align__(16) bf16 Bs[2][2][128 * 32];   // 32 KB
  __shared__ __align__(16) bf16 Alds[128 * 64];       // 16 KB swizzled A-image

  const int g = blockIdx.x, xcd = g & 7, s = g >> 3;
  const int nb = s % 6, mh = s / 6;
  const int m0 = (mh * 8 + xcd) * 128;
  const float* A = (nb < 2) ? q : kv;

  const int tid = threadIdx.x, lane = tid & 63, wave = tid >> 6;
  const int lm = lane & 15, lq = lane >> 4;
  const int swzlq = lq ^ ((lm >> 1) & 3);
  const int mw = wave * 32;

  f32x4 acc[2][8];
#pragma unroll
  for (int t = 0; t < 2; ++t)
#pragma unroll
    for (int nf = 0; nf < 8; ++nf) acc[t][nf] = (f32x4)0.0f;

  const bf16* pbase = packQ + (size_t)nb * 4 * 8192;

  // A staging: thread owns (row = u*16 + tid>>4, 16B f32 chunk c16 = tid&15)
  const int arow = tid >> 4;        // +u*16
  const int ac16 = tid & 15;        // f32 cols ac16*4..+3
  float4 ar[8];                     // one k-slice of A, static-indexed

  auto loadA = [&](int it) {
#pragma unroll
    for (int u = 0; u < 8; ++u) {
      const int row = u * 16 + arow;
      ar[u] = *(const float4*)(A + (size_t)(m0 + row) * 256 + it * 64 + ac16 * 4);
    }
  };
  auto writeA = [&]() {
    const int gsl = ac16 >> 1, half = ac16 & 1;
#pragma unroll
    for (int u = 0; u < 8; ++u) {
      const int row = u * 16 + arow;
      const float4 f = ar[u];
      bf16x4 v;
      v[0] = (bf16)f.x; v[1] = (bf16)f.y; v[2] = (bf16)f.z; v[3] = (bf16)f.w;
      *(bf16x4*)&Alds[row * 64 + ((gsl ^ (row & 7)) << 3) + half * 4] = v;
    }
  };
  auto stageB = [&](int it, int buf) {
    const bf16* pit = pbase + it * 8192;
#pragma unroll
    for (int u = 0; u < 4; ++u) {
      const int c = u * 256 + tid;
      bf16* dst = (u < 2) ? &Bs[buf][0][c * 8] : &Bs[buf][1][(c - 512) * 8];
      gll16(pit + c * 8, dst);
    }
  };

  // prologue: A(0) -> regs -> image; B(0) -> LDS buf0
  loadA(0);
  writeA();
  stageB(0, 0);
  __syncthreads();

#pragma unroll
  for (int i = 0; i < 4; ++i) {
    const int cur = i & 1;
    if (i < 3) {
      stageB(i + 1, cur ^ 1);   // in flight across compute
      loadA(i + 1);             // in flight across compute
    }
    // compute on Alds (iter i image) and Bs[cur]
#pragma unroll
    for (int ks = 0; ks < 2; ++ks) {
      bf16x8 av[2], bvf[8];
#pragma unroll
      for (int t = 0; t < 2; ++t) {
        const int row = mw + t * 16 + lm;
        av[t] = *(const bf16x8*)&Alds[row * 64 + (((ks * 4 + lq) ^ (lm & 7)) << 3)];
      }
#pragma unroll
      for (int nf = 0; nf < 8; ++nf)
        bvf[nf] = *(const bf16x8*)&Bs[cur][ks][(nf * 16 + lm) * 32 + swzlq * 8];
#pragma unroll
      for (int t = 0; t < 2; ++t)
#pragma unroll
        for (int nf = 0; nf < 8; ++nf)
          acc[t][nf] = __builtin_amdgcn_mfma_f32_16x16x32_bf16(av[t], bvf[nf], acc[t][nf], 0, 0, 0);
    }
    if (i < 3) {
      __syncthreads();   // all reads of Alds done; drains B(i+1)/A(i+1) loads (overlapped by compute)
      writeA();          // overwrite A-image with iter i+1 slice
      __syncthreads();   // image visible
    }
  }

  // Epilogue. C layout: col = lane&15, row = (lane>>4)*4 + reg.
  const int ncbase = (nb * 128) & 255;
  bf16* op = (nb < 2) ? qp : (nb < 4) ? kp : vp;
  const float* bp = (nb < 2) ? bq : (nb < 4) ? bk : bvv;
#pragma unroll
  for (int t = 0; t < 2; ++t)
#pragma unroll
    for (int nf = 0; nf < 8; ++nf) {
      const int nc = ncbase + nf * 16 + lm;
      const float bval = bp[nc];
#pragma unroll
      for (int r = 0; r < 4; ++r) {
        const int mg = m0 + mw + t * 16 + lq * 4 + r;
        op[(size_t)mg * 256 + nc] = (bf16)(acc[t][nf][r] + bval);
      }
    }
}

// ---------------------------------------------------------------------------
// Output projection: exact 2-term as K=512 GEMM (iters 0-3 hi, 4-7 lo; A
// re-read, L2-hot on 2nd pass). Same r7 template as k_qkv: A (bf16 ao)
// loaded linearly to regs (per instr: 8 rows x 128B = 8x128B segments),
// ds_write_b128 to swizzled A-image; B double-buffered via gll16 from
// swizzled packO. 2 barriers/iter. Accumulation order unchanged.
// ---------------------------------------------------------------------------
__global__ __launch_bounds__(256, 3) void k_oproj(
    const bf16* __restrict__ ao, const bf16* __restrict__ packO,
    const float* __restrict__ bo, float* __restrict__ out) {
  __shared__ __align__(16) bf16 Bs[2][2][128 * 32];   // 32 KB
  __shared__ __align__(16) bf16 Alds[128 * 64];       // 16 KB swizzled A-image

  const int g = blockIdx.x, xcd = g & 7, s = g >> 3;
  const int nb = s & 1, mh = s >> 1;
  const int m0 = (mh * 8 + xcd) * 128;

  const int tid = threadIdx.x, lane = tid & 63, wave = tid >> 6;
  const int lm = lane & 15, lq = lane >> 4;
  const int swzlq = lq ^ ((lm >> 1) & 3);
  const int mw = wave * 32;

  f32x4 acc[2][8];
#pragma unroll
  for (int t = 0; t < 2; ++t)
#pragma unroll
    for (int nf = 0; nf < 8; ++nf) acc[t][nf] = (f32x4)0.0f;

  const bf16* pbase = packO + (size_t)nb * 8 * 8192;

  // A staging: chunk cc = u*256+tid over [128 rows][8 chunks of 8 bf16]
  const int arow = tid >> 3;        // +u*32
  const int ach  = tid & 7;         // 16B chunk within row slice
  bf16x8 arv[4];                    // one k-slice, static-indexed

  auto loadA = [&](int it) {
    const int kA = (it & 3) * 64;   // iters 4-7 re-read same A (hi/lo terms)
#pragma unroll
    for (int u = 0; u < 4; ++u) {
      const int row = u * 32 + arow;
      arv[u] = *(const bf16x8*)(ao + (size_t)(m0 + row) * 256 + kA + ach * 8);
    }
  };
  auto writeA = [&]() {
#pragma unroll
    for (int u = 0; u < 4; ++u) {
      const int row = u * 32 + arow;
      *(bf16x8*)&Alds[row * 64 + ((ach ^ (row & 7)) << 3)] = arv[u];
    }
  };
  auto stageB = [&](int it, int buf) {
    const bf16* pit = pbase + (size_t)it * 8192;
#pragma unroll
    for (int u = 0; u < 4; ++u) {
      const int c = u * 256 + tid;
      bf16* dst = (u < 2) ? &Bs[buf][0][c * 8] : &Bs[buf][1][(c - 512) * 8];
      gll16(pit + c * 8, dst);
    }
  };

  loadA(0);
  writeA();
  stageB(0, 0);
  __syncthreads();

#pragma unroll
  for (int i = 0; i < 8; ++i) {
    const int cur = i & 1;
    if (i < 7) {
      stageB(i + 1, cur ^ 1);
      loadA(i + 1);
    }
#pragma unroll
    for (int ks = 0; ks < 2; ++ks) {
      bf16x8 av[2], bvf[8];
#pragma unroll
      for (int t = 0; t < 2; ++t) {
        const int row = mw + t * 16 + lm;
        av[t] = *(const bf16x8*)&Alds[row * 64 + (((ks * 4 + lq) ^ (lm & 7)) << 3)];
      }
#pragma unroll
      for (int nf = 0; nf < 8; ++nf)
        bvf[nf] = *(const bf16x8*)&Bs[cur][ks][(nf * 16 + lm) * 32 + swzlq * 8];
#pragma unroll
      for (int t = 0; t < 2; ++t)
#pragma unroll
        for (int nf = 0; nf < 8; ++nf)
          acc[t][nf] = __builtin_amdgcn_mfma_f32_16x16x32_bf16(av[t], bvf[nf], acc[t][nf], 0, 0, 0);
    }
    if (i < 7) {
      __syncthreads();
      writeA();
      __syncthreads();
    }
  }

  // Epilogue. C layout: col = lane&15, row = (lane>>4)*4 + reg. f32 out.
#pragma unroll
  for (int t = 0; t < 2; ++t)
#pragma unroll
    for (int nf = 0; nf < 8; ++nf) {
      const int nglob = nb * 128 + nf * 16 + lm;
      const float bval = bo[nglob];
#pragma unroll
      for (int r = 0; r < 4; ++r) {
        const int mg = m0 + mw + t * 16 + lq * 4 + r;
        out[(size_t)mg * 256 + nglob] = acc[t][nf][r] + bval;
      }
    }
}

// ---------------------------------------------------------------------------
// Windowed attention (unchanged).
// ---------------------------------------------------------------------------
__global__ __launch_bounds__(256) void k_attn(
    const bf16* __restrict__ qp, const bf16* __restrict__ kp,
    const bf16* __restrict__ vp, bf16* __restrict__ ao) {
  __shared__ __align__(16) bf16 smem[3 * 64 * 136];
  bf16* Qs = smem;
  bf16* Ks = smem + 64 * 136;
  bf16* Vs = smem + 2 * 64 * 136;
  bf16* Ps = smem;
  bf16* Os = Vs;

  const int tid = threadIdx.x;
  const int lane = tid & 63;
  const int hl = tid >> 6;
  const int bw = blockIdx.x;
  const int b = bw >> 8;
  const int w = bw & 255;
  const int wy = w >> 4, wx = w & 15;
  const int ch0 = blockIdx.y * 128;

#pragma unroll
  for (int i = 0; i < 4; ++i) {
    const int c = i * 256 + tid;
    const int t = c >> 4;
    const int off = (c & 15) * 8;
    const int ty = t >> 3, tx = t & 7;
    const size_t gr = ((size_t)(b * 128 + wy * 8 + ty)) * 128 + wx * 8 + tx;
    const size_t gi = gr * 256 + ch0 + off;
    const int li = t * 136 + off;
    *(uint4*)&Qs[li] = *(const uint4*)&qp[gi];
    *(uint4*)&Ks[li] = *(const uint4*)&kp[gi];
    *(uint4*)&Vs[li] = *(const uint4*)&vp[gi];
  }
  __syncthreads();

  const int chh = hl * 32;
  const int lm = lane & 15;
  const int lq = lane >> 4;

  bf16x8 qa[4], kb[4];
#pragma unroll
  for (int t = 0; t < 4; ++t)
    qa[t] = *(const bf16x8*)&Qs[(t * 16 + lm) * 136 + chh + lq * 8];
#pragma unroll
  for (int t = 0; t < 4; ++t)
    kb[t] = *(const bf16x8*)&Ks[(t * 16 + lm) * 136 + chh + lq * 8];

  f32x4 s[4][4];
#pragma unroll
  for (int i = 0; i < 4; ++i)
#pragma unroll
    for (int j = 0; j < 4; ++j) s[i][j] = (f32x4)0.0f;
#pragma unroll
  for (int i = 0; i < 4; ++i)
#pragma unroll
    for (int j = 0; j < 4; ++j)
      s[i][j] = __builtin_amdgcn_mfma_f32_16x16x32_bf16(qa[i], kb[j], s[i][j], 0, 0, 0);

  const float scale = 0.17677669529663687f;
  float rl[4][4];
#pragma unroll
  for (int mt = 0; mt < 4; ++mt) {
#pragma unroll
    for (int r = 0; r < 4; ++r) {
      float mx = fmaxf(fmaxf(s[mt][0][r], s[mt][1][r]), fmaxf(s[mt][2][r], s[mt][3][r]));
      mx = fmaxf(mx, __shfl_xor(mx, 1));
      mx = fmaxf(mx, __shfl_xor(mx, 2));
      mx = fmaxf(mx, __shfl_xor(mx, 4));
      mx = fmaxf(mx, __shfl_xor(mx, 8));
      float sum = 0.f;
#pragma unroll
      for (int nt = 0; nt < 4; ++nt) {
        const float p = __expf((s[mt][nt][r] - mx) * scale);
        s[mt][nt][r] = p;
        sum += p;
      }
      sum += __shfl_xor(sum, 1);
      sum += __shfl_xor(sum, 2);
      sum += __shfl_xor(sum, 4);
      sum += __shfl_xor(sum, 8);
      rl[mt][r] = 1.0f / sum;
    }
  }

  __syncthreads();

  bf16* Ph = Ps + hl * 4096;
#pragma unroll
  for (int mt = 0; mt < 4; ++mt)
#pragma unroll
    for (int nt = 0; nt < 4; ++nt)
#pragma unroll
      for (int r = 0; r < 4; ++r) {
        const int qrow = mt * 16 + lq * 4 + r;
        const int kcol = nt * 16 + lm;
        Ph[qrow * 64 + (((kcol >> 3) ^ (qrow & 7)) << 3) + (kcol & 7)] = (bf16)s[mt][nt][r];
      }

  f32x4 o[4][2];
#pragma unroll
  for (int i = 0; i < 4; ++i) { o[i][0] = (f32x4)0.0f; o[i][1] = (f32x4)0.0f; }
#pragma unroll
  for (int ks = 0; ks < 2; ++ks) {
    bf16x8 pa[4];
#pragma unroll
    for (int mt = 0; mt < 4; ++mt) {
      const int qrow = mt * 16 + lm;
      const int gsel = ks * 4 + lq;
      pa[mt] = *(const bf16x8*)&Ph[qrow * 64 + ((gsel ^ (qrow & 7)) << 3)];
    }
    bf16x8 vbf[2];
#pragma unroll
    for (int ntd = 0; ntd < 2; ++ntd) {
      const int d = ntd * 16 + lm;
      bf16x8 tv;
#pragma unroll
      for (int j = 0; j < 8; ++j)
        tv[j] = Vs[(ks * 32 + lq * 8 + j) * 136 + chh + d];
      vbf[ntd] = tv;
    }
#pragma unroll
    for (int mt = 0; mt < 4; ++mt)
#pragma unroll
      for (int ntd = 0; ntd < 2; ++ntd)
        o[mt][ntd] = __builtin_amdgcn_mfma_f32_16x16x32_bf16(pa[mt], vbf[ntd], o[mt][ntd], 0, 0, 0);
  }

  __syncthreads();

#pragma unroll
  for (int mt = 0; mt < 4; ++mt)
#pragma unroll
    for (int ntd = 0; ntd < 2; ++ntd)
#pragma unroll
      for (int r = 0; r < 4; ++r) {
        const int qrow = mt * 16 + lq * 4 + r;
        const int d = ntd * 16 + lm;
        Os[qrow * 136 + chh + d] = (bf16)(o[mt][ntd][r] * rl[mt][r]);
      }
  __syncthreads();

#pragma unroll
  for (int i = 0; i < 4; ++i) {
    const int c = i * 256 + tid;
    const int t = c >> 4;
    const int off = (c & 15) * 8;
    const int ty = t >> 3, tx = t & 7;
    const size_t gr = ((size_t)(b * 128 + wy * 8 + ty)) * 128 + wx * 8 + tx;
    *(uint4*)&ao[gr * 256 + ch0 + off] = *(const uint4*)&Os[t * 136 + off];
  }
}

// ---------------------------------------------------------------------------
extern "C" void kernel_launch(void* const* d_in, const int* in_sizes, int n_in,
                              void* d_out, int out_size, void* d_ws, size_t ws_size,
                              hipStream_t stream) {
  const float* q  = (const float*)d_in[0];
  const float* kv = (const float*)d_in[1];
  const float* Wq = (const float*)d_in[2];
  const float* bq = (const float*)d_in[3];
  const float* Wk = (const float*)d_in[4];
  const float* bk = (const float*)d_in[5];
  const float* Wv = (const float*)d_in[6];
  const float* bv = (const float*)d_in[7];
  const float* Wo = (const float*)d_in[8];
  const float* bo = (const float*)d_in[9];
  float* out = (float*)d_out;

  char* ws = (char*)d_ws;
  bf16* packQ = (bf16*)(ws + 0);        // 393216 B
  bf16* packO = (bf16*)(ws + 393216);   // 262144 B
  const size_t PLANE = (size_t)65536 * 256 * 2;
  bf16* qp = (bf16*)(ws + 1048576);
  bf16* kp = (bf16*)(ws + 1048576 + PLANE);
  bf16* vp = (bf16*)(ws + 1048576 + 2 * PLANE);
  bf16* ao = (bf16*)(ws + 1048576 + 3 * PLANE);
  if (ws_size < 1048576 + 4 * PLANE) return;

  k_prep<<<dim3(256, 5), 256, 0, stream>>>(Wq, Wk, Wv, Wo, packQ, packO);
  k_qkv<<<3072, 256, 0, stream>>>(q, kv, packQ, bq, bk, bv, qp, kp, vp);
  k_attn<<<dim3(1024, 2), 256, 0, stream>>>(qp, kp, vp, ao);
  k_oproj<<<1024, 256, 0, stream>>>(ao, packO, bo, out);
}